// Round 13
// baseline (110.245 us; speedup 1.0000x reference)
//
#include <hip/hip_runtime.h>

typedef float v2f __attribute__((ext_vector_type(2)));

// ---------------------------------------------------------------------------
// Cross-lane helpers: masks 1,2,8 via DPP (VALU pipe), mask 4 via ds_swizzle;
// ds_bpermute only for the one-time angle gather.
// ---------------------------------------------------------------------------
template<int C>
__device__ __forceinline__ float dppmov(float x) {
  return __int_as_float(__builtin_amdgcn_update_dpp(0, __float_as_int(x), C, 0xF, 0xF, true));
}
template<int IMM>
__device__ __forceinline__ float dswz(float x) {
  return __int_as_float(__builtin_amdgcn_ds_swizzle(__float_as_int(x), IMM));
}
__device__ __forceinline__ float bperm(float x, int a) {
  return __int_as_float(__builtin_amdgcn_ds_bpermute(a, __float_as_int(x)));
}
template<int M>
__device__ __forceinline__ float bfly(float x) {
  if constexpr (M == 1)      return dppmov<0xB1>(x);   // quad_perm [1,0,3,2]
  else if constexpr (M == 2) return dppmov<0x4E>(x);   // quad_perm [2,3,0,1]
  else if constexpr (M == 8) return dppmov<0x128>(x);  // row_ror:8 == xor8
  else                       return dswz<0x101F>(x);   // M==4: bit-mode xor4
}
template<int M>
__device__ __forceinline__ v2f bfly2(v2f v) {
  v2f o; o.x = bfly<M>(v.x); o.y = bfly<M>(v.y); return o;
}
__device__ __forceinline__ v2f sp(float s) { v2f v; v.x = s; v.y = s; return v; }
__device__ __forceinline__ v2f vfma(v2f a, v2f b, v2f c) {
  return __builtin_elementwise_fma(a, b, c);
}

// ---------------------------------------------------------------------------
// Layout: 16 pixels/wave as TWO independent chains P,Q (each = round-7/11
// layout: group g = lane>>4 holds a packed pixel pair in v2f; amp i = q*16+r,
// q = lane&15; wires 0..3 <-> q bits 3..0; wires 4..7 <-> r bits 3..0).
// Chain P covers pixels p0..p0+7, chain Q covers p0+8..p0+15. Gate
// coefficients are computed once per wave and shared by both chains.
// ---------------------------------------------------------------------------
template<int M, int CM>
__device__ __forceinline__ void crossGD(v2f Pr[16], v2f Pi[16],
    v2f Qr[16], v2f Qi[16], const float* g, int lane) {
  const bool hi = (lane & M) != 0;
  float fr, fi, gr, gi;
  if constexpr (CM == 0) {
    fr = hi ? g[6] : g[0]; fi = hi ? g[7] : g[1];
    gr = hi ? g[4] : g[2]; gi = hi ? g[5] : g[3];
  } else {
    const bool ct = (lane & CM) != 0;
    float f0r = hi ? g[6]  : g[0],  f0i = hi ? g[7]  : g[1];
    float g0r = hi ? g[4]  : g[2],  g0i = hi ? g[5]  : g[3];
    float f1r = hi ? g[14] : g[8],  f1i = hi ? g[15] : g[9];
    float g1r = hi ? g[12] : g[10], g1i = hi ? g[13] : g[11];
    fr = ct ? f1r : f0r; fi = ct ? f1i : f0i;
    gr = ct ? g1r : g0r; gi = ct ? g1i : g0i;
  }
  v2f vfr = sp(fr), vfi = sp(fi), vgr = sp(gr), vgi = sp(gi);
  v2f vfiN = sp(-fi), vgiN = sp(-gi);
#pragma unroll
  for (int r = 0; r < 16; ++r) {
    v2f pR = bfly2<M>(Pr[r]);
    v2f pI = bfly2<M>(Pi[r]);
    v2f qR = bfly2<M>(Qr[r]);
    v2f qI = bfly2<M>(Qi[r]);
    v2f nPR = vfma(vgiN, pI, vfma(vgr, pR, vfma(vfiN, Pi[r], vfr * Pr[r])));
    v2f nPI = vfma(vgi,  pR, vfma(vgr, pI, vfma(vfi,  Pr[r], vfr * Pi[r])));
    v2f nQR = vfma(vgiN, qI, vfma(vgr, qR, vfma(vfiN, Qi[r], vfr * Qr[r])));
    v2f nQI = vfma(vgi,  qR, vfma(vgr, qI, vfma(vfi,  Qr[r], vfr * Qi[r])));
    Pr[r] = nPR; Pi[r] = nPI; Qr[r] = nQR; Qi[r] = nQI;
  }
}

__device__ __forceinline__ void mixP(v2f& x0r, v2f& x0i, v2f& x1r, v2f& x1i,
    float m0r, float m0i, float m1r, float m1i,
    float m2r, float m2i, float m3r, float m3i) {
  v2f n0r = vfma(sp(-m1i), x1i, vfma(sp(m1r), x1r, vfma(sp(-m0i), x0i, sp(m0r) * x0r)));
  v2f n0i = vfma(sp( m1i), x1r, vfma(sp(m1r), x1i, vfma(sp( m0i), x0r, sp(m0r) * x0i)));
  v2f n1r = vfma(sp(-m3i), x1i, vfma(sp(m3r), x1r, vfma(sp(-m2i), x0i, sp(m2r) * x0r)));
  v2f n1i = vfma(sp( m3i), x1r, vfma(sp(m3r), x1i, vfma(sp( m2i), x0r, sp(m2r) * x0i)));
  x0r = n0r; x0i = n0i; x1r = n1r; x1i = n1i;
}

// F4: fused u3(w4)+cu3(3->4): ctrl lane bit0 (wire 3), target r bit3.
__device__ __forceinline__ void f4D(v2f Pr[16], v2f Pi[16],
    v2f Qr[16], v2f Qi[16], const float* g, int lane) {
  const bool ct = (lane & 1) != 0;
  float m[8];
#pragma unroll
  for (int jj = 0; jj < 8; ++jj) m[jj] = ct ? g[8 + jj] : g[jj];
#pragma unroll
  for (int r = 0; r < 8; ++r) {
    mixP(Pr[r], Pi[r], Pr[r + 8], Pi[r + 8],
         m[0], m[1], m[2], m[3], m[4], m[5], m[6], m[7]);
    mixP(Qr[r], Qi[r], Qr[r + 8], Qi[r + 8],
         m[0], m[1], m[2], m[3], m[4], m[5], m[6], m[7]);
  }
}
// F5: ctrl r bit3, target r bit2.
__device__ __forceinline__ void f5D(v2f Pr[16], v2f Pi[16],
    v2f Qr[16], v2f Qi[16], const float* g) {
#pragma unroll
  for (int r = 0; r < 4; ++r) {
    mixP(Pr[r], Pi[r], Pr[r + 4], Pi[r + 4],
         g[0], g[1], g[2], g[3], g[4], g[5], g[6], g[7]);
    mixP(Qr[r], Qi[r], Qr[r + 4], Qi[r + 4],
         g[0], g[1], g[2], g[3], g[4], g[5], g[6], g[7]);
  }
#pragma unroll
  for (int r = 8; r < 12; ++r) {
    mixP(Pr[r], Pi[r], Pr[r + 4], Pi[r + 4],
         g[8], g[9], g[10], g[11], g[12], g[13], g[14], g[15]);
    mixP(Qr[r], Qi[r], Qr[r + 4], Qi[r + 4],
         g[8], g[9], g[10], g[11], g[12], g[13], g[14], g[15]);
  }
}
// F6: ctrl r bit2, target r bit1.
__device__ __forceinline__ void f6D(v2f Pr[16], v2f Pi[16],
    v2f Qr[16], v2f Qi[16], const float* g) {
#pragma unroll
  for (int t = 0; t < 4; ++t) {
    const int r0 = (t >> 1) * 8 + (t & 1);
    mixP(Pr[r0], Pi[r0], Pr[r0 + 2], Pi[r0 + 2],
         g[0], g[1], g[2], g[3], g[4], g[5], g[6], g[7]);
    mixP(Qr[r0], Qi[r0], Qr[r0 + 2], Qi[r0 + 2],
         g[0], g[1], g[2], g[3], g[4], g[5], g[6], g[7]);
    const int r1 = r0 + 4;
    mixP(Pr[r1], Pi[r1], Pr[r1 + 2], Pi[r1 + 2],
         g[8], g[9], g[10], g[11], g[12], g[13], g[14], g[15]);
    mixP(Qr[r1], Qi[r1], Qr[r1 + 2], Qi[r1 + 2],
         g[8], g[9], g[10], g[11], g[12], g[13], g[14], g[15]);
  }
}
// F7: ctrl r bit1, target r bit0.
__device__ __forceinline__ void f7D(v2f Pr[16], v2f Pi[16],
    v2f Qr[16], v2f Qi[16], const float* g) {
#pragma unroll
  for (int t = 0; t < 4; ++t) {
    const int r0 = t * 4;
    mixP(Pr[r0], Pi[r0], Pr[r0 + 1], Pi[r0 + 1],
         g[0], g[1], g[2], g[3], g[4], g[5], g[6], g[7]);
    mixP(Qr[r0], Qi[r0], Qr[r0 + 1], Qi[r0 + 1],
         g[0], g[1], g[2], g[3], g[4], g[5], g[6], g[7]);
    const int r1 = r0 + 2;
    mixP(Pr[r1], Pi[r1], Pr[r1 + 1], Pi[r1 + 1],
         g[8], g[9], g[10], g[11], g[12], g[13], g[14], g[15]);
    mixP(Qr[r1], Qi[r1], Qr[r1 + 1], Qi[r1 + 1],
         g[8], g[9], g[10], g[11], g[12], g[13], g[14], g[15]);
  }
}
// F8': fused cu3(7->0)+next u3(w0): ctrl r bit0, target mask 8.
__device__ __forceinline__ void f8pD(v2f Pr[16], v2f Pi[16],
    v2f Qr[16], v2f Qi[16], const float* g, int lane) {
  const bool hi = (lane & 8) != 0;
  float fr[2], fi[2], gr[2], gi[2];
  fr[0] = hi ? g[6]  : g[0];  fi[0] = hi ? g[7]  : g[1];
  gr[0] = hi ? g[4]  : g[2];  gi[0] = hi ? g[5]  : g[3];
  fr[1] = hi ? g[14] : g[8];  fi[1] = hi ? g[15] : g[9];
  gr[1] = hi ? g[12] : g[10]; gi[1] = hi ? g[13] : g[11];
#pragma unroll
  for (int r = 0; r < 16; ++r) {
    const int m = r & 1;
    v2f pR = bfly2<8>(Pr[r]);
    v2f pI = bfly2<8>(Pi[r]);
    v2f qR = bfly2<8>(Qr[r]);
    v2f qI = bfly2<8>(Qi[r]);
    v2f nPR = vfma(sp(-gi[m]), pI, vfma(sp(gr[m]), pR, vfma(sp(-fi[m]), Pi[r], sp(fr[m]) * Pr[r])));
    v2f nPI = vfma(sp( gi[m]), pR, vfma(sp(gr[m]), pI, vfma(sp( fi[m]), Pr[r], sp(fr[m]) * Pi[r])));
    v2f nQR = vfma(sp(-gi[m]), qI, vfma(sp(gr[m]), qR, vfma(sp(-fi[m]), Qi[r], sp(fr[m]) * Qr[r])));
    v2f nQI = vfma(sp( gi[m]), qR, vfma(sp(gr[m]), qI, vfma(sp( fi[m]), Qr[r], sp(fr[m]) * Qi[r])));
    Pr[r] = nPR; Pi[r] = nPI; Qr[r] = nQR; Qi[r] = nQI;
  }
}
// F8 final standalone cu3(7->0): odd r only, target mask 8.
__device__ __forceinline__ void f8D(v2f Pr[16], v2f Pi[16],
    v2f Qr[16], v2f Qi[16], const float* g, int lane) {
  const bool hi = (lane & 8) != 0;
  const float fr = hi ? g[6] : g[0], fi = hi ? g[7] : g[1];
  const float gr = hi ? g[4] : g[2], gi = hi ? g[5] : g[3];
#pragma unroll
  for (int r = 1; r < 16; r += 2) {
    v2f pR = bfly2<8>(Pr[r]);
    v2f pI = bfly2<8>(Pi[r]);
    v2f qR = bfly2<8>(Qr[r]);
    v2f qI = bfly2<8>(Qi[r]);
    v2f nPR = vfma(sp(-gi), pI, vfma(sp(gr), pR, vfma(sp(-fi), Pi[r], sp(fr) * Pr[r])));
    v2f nPI = vfma(sp( gi), pR, vfma(sp(gr), pI, vfma(sp( fi), Pr[r], sp(fr) * Pi[r])));
    v2f nQR = vfma(sp(-gi), qI, vfma(sp(gr), qR, vfma(sp(-fi), Qi[r], sp(fr) * Qr[r])));
    v2f nQI = vfma(sp( gi), qR, vfma(sp(gr), qI, vfma(sp( fi), Qr[r], sp(fr) * Qi[r])));
    Pr[r] = nPR; Pi[r] = nPI; Qr[r] = nQR; Qi[r] = nQI;
  }
}

// Off-diagonal pair sum for a cross wire (mask M): per-lane partials.
template<int M>
__device__ __forceinline__ void crossO(const v2f Sr[16], const v2f Si[16],
                                       v2f& re, v2f& im) {
  v2f r = sp(0.0f), i = sp(0.0f);
#pragma unroll
  for (int k = 0; k < 16; ++k) {
    v2f pr = bfly2<M>(Sr[k]);
    v2f pi = bfly2<M>(Si[k]);
    r = vfma(Sr[k], pr, r);
    r = vfma(Si[k], pi, r);
    i = vfma(Si[k], pr, i);
    i = vfma(-Sr[k], pi, i);
  }
  re = r; im = i;
}

// Per-lane measurement partials (24) for one chain.
__device__ __forceinline__ void partials(const v2f Sr[16], const v2f Si[16],
                                         const float* sg, v2f PT[24]) {
  v2f re0, im0, re1, im1, re2, im2, re3, im3;
  crossO<8>(Sr, Si, re0, im0);
  crossO<4>(Sr, Si, re1, im1);
  crossO<2>(Sr, Si, re2, im2);
  crossO<1>(Sr, Si, re3, im3);
  PT[8]  = re0; PT[9]  = re1; PT[10] = re2; PT[11] = re3;
  PT[16] = sp(sg[0]) * im0; PT[17] = sp(sg[1]) * im1;
  PT[18] = sp(sg[2]) * im2; PT[19] = sp(sg[3]) * im3;

  v2f P[16];
#pragma unroll
  for (int r = 0; r < 16; ++r) P[r] = vfma(Si[r], Si[r], Sr[r] * Sr[r]);
  v2f t01[8];
#pragma unroll
  for (int k = 0; k < 8; ++k) t01[k] = P[2*k] + P[2*k+1];
  v2f q0 = t01[0] + t01[1], q1 = t01[2] + t01[3];
  v2f q2 = t01[4] + t01[5], q3 = t01[6] + t01[7];
  v2f h0 = q0 + q1, h1 = q2 + q3;
  v2f p  = h0 + h1;
  PT[4] = h0 - h1;
  PT[5] = (q0 - q1) + (q2 - q3);
  PT[6] = (t01[0]-t01[1]) + (t01[2]-t01[3]) + (t01[4]-t01[5]) + (t01[6]-t01[7]);
  PT[7] = (P[0]-P[1]) + (P[2]-P[3]) + (P[4]-P[5]) + (P[6]-P[7])
        + (P[8]-P[9]) + (P[10]-P[11]) + (P[12]-P[13]) + (P[14]-P[15]);
  PT[0] = sp(sg[0]) * p; PT[1] = sp(sg[1]) * p;
  PT[2] = sp(sg[2]) * p; PT[3] = sp(sg[3]) * p;

  v2f re, im;
  re = sp(0.0f); im = sp(0.0f);
#pragma unroll
  for (int r = 0; r < 8; ++r) {
    re = vfma(Sr[r], Sr[r+8], re); re = vfma(Si[r], Si[r+8], re);
    im = vfma(Si[r], Sr[r+8], im); im = vfma(-Sr[r], Si[r+8], im);
  }
  PT[12] = re; PT[20] = im;
  re = sp(0.0f); im = sp(0.0f);
#pragma unroll
  for (int t = 0; t < 8; ++t) {
    const int lo = (t & 3) + (t >> 2) * 8;
    re = vfma(Sr[lo], Sr[lo+4], re); re = vfma(Si[lo], Si[lo+4], re);
    im = vfma(Si[lo], Sr[lo+4], im); im = vfma(-Sr[lo], Si[lo+4], im);
  }
  PT[13] = re; PT[21] = im;
  re = sp(0.0f); im = sp(0.0f);
#pragma unroll
  for (int t = 0; t < 8; ++t) {
    const int lo = (t & 1) + (t >> 1) * 4;
    re = vfma(Sr[lo], Sr[lo+2], re); re = vfma(Si[lo], Si[lo+2], re);
    im = vfma(Si[lo], Sr[lo+2], im); im = vfma(-Sr[lo], Si[lo+2], im);
  }
  PT[14] = re; PT[22] = im;
  re = sp(0.0f); im = sp(0.0f);
#pragma unroll
  for (int t = 0; t < 8; ++t) {
    const int lo = 2 * t;
    re = vfma(Sr[lo], Sr[lo+1], re); re = vfma(Si[lo], Si[lo+1], re);
    im = vfma(Si[lo], Sr[lo+1], im); im = vfma(-Sr[lo], Si[lo+1], im);
  }
  PT[15] = re; PT[23] = im;
}

// Build RY-product state (with F0 folded) for one chain from gathered angles.
__device__ __forceinline__ void initChain(const float aA[8], const float aB[8],
    const float* Gs, int q, v2f Sr[16], v2f Si[16]) {
  float cA[8], sA[8], cB[8], sB[8];
#pragma unroll
  for (int w = 0; w < 8; ++w) {
    __sincosf(0.5f * aA[w], &sA[w], &cA[w]);
    __sincosf(0.5f * aB[w], &sB[w], &cB[w]);
  }
  v2f c0; c0.x = cA[0]; c0.y = cB[0];
  v2f s0; s0.x = sA[0]; s0.y = sB[0];
  v2f c0r = vfma(sp(Gs[2]), s0, sp(Gs[0]) * c0);
  v2f c0i = vfma(sp(Gs[3]), s0, sp(Gs[1]) * c0);
  v2f s0r = vfma(sp(Gs[6]), s0, sp(Gs[4]) * c0);
  v2f s0i = vfma(sp(Gs[7]), s0, sp(Gs[5]) * c0);
  const bool w0 = (q & 8) != 0;
  v2f selR = w0 ? s0r : c0r;
  v2f selI = w0 ? s0i : c0i;
  float fA = ((q & 4) ? sA[1] : cA[1]) * ((q & 2) ? sA[2] : cA[2])
           * ((q & 1) ? sA[3] : cA[3]);
  float fB = ((q & 4) ? sB[1] : cB[1]) * ((q & 2) ? sB[2] : cB[2])
           * ((q & 1) ? sB[3] : cB[3]);
  v2f uu[4], vv[4];
  uu[0].x = cA[6]*cA[7]; uu[1].x = cA[6]*sA[7];
  uu[2].x = sA[6]*cA[7]; uu[3].x = sA[6]*sA[7];
  uu[0].y = cB[6]*cB[7]; uu[1].y = cB[6]*sB[7];
  uu[2].y = sB[6]*cB[7]; uu[3].y = sB[6]*sB[7];
  float vA0 = fA * cA[4], vA1 = fA * sA[4];
  float vB0 = fB * cB[4], vB1 = fB * sB[4];
  vv[0].x = vA0*cA[5]; vv[1].x = vA0*sA[5];
  vv[2].x = vA1*cA[5]; vv[3].x = vA1*sA[5];
  vv[0].y = vB0*cB[5]; vv[1].y = vB0*sB[5];
  vv[2].y = vB1*cB[5]; vv[3].y = vB1*sB[5];
#pragma unroll
  for (int r = 0; r < 16; ++r) {
    v2f base = vv[r >> 2] * uu[r & 3];
    Sr[r] = selR * base;
    Si[r] = selI * base;
  }
}

// ---------------------------------------------------------------------------
// Prep helpers.
// ---------------------------------------------------------------------------
__device__ __forceinline__ void mm2(const float* A, const float* B, float* D) {
  D[0] = A[0]*B[0] - A[1]*B[1] + A[2]*B[4] - A[3]*B[5];
  D[1] = A[0]*B[1] + A[1]*B[0] + A[2]*B[5] + A[3]*B[4];
  D[2] = A[0]*B[2] - A[1]*B[3] + A[2]*B[6] - A[3]*B[7];
  D[3] = A[0]*B[3] + A[1]*B[2] + A[2]*B[7] + A[3]*B[6];
  D[4] = A[4]*B[0] - A[5]*B[1] + A[6]*B[4] - A[7]*B[5];
  D[5] = A[4]*B[1] + A[5]*B[0] + A[6]*B[5] + A[7]*B[4];
  D[6] = A[4]*B[2] - A[5]*B[3] + A[6]*B[6] - A[7]*B[7];
  D[7] = A[4]*B[3] + A[5]*B[2] + A[6]*B[7] + A[7]*B[6];
}
__device__ __forceinline__ void u3fill(const float* src, float* o) {
  float th = src[0], ph = src[1], lam = src[2];
  float c = cosf(0.5f * th), s = sinf(0.5f * th);
  float cl = cosf(lam), sl = sinf(lam);
  float cp = cosf(ph), spv = sinf(ph);
  float cpl = cosf(ph + lam), spl = sinf(ph + lam);
  o[0] = c;        o[1] = 0.0f;
  o[2] = -cl * s;  o[3] = -sl * s;
  o[4] = cp * s;   o[5] = spv * s;
  o[6] = cpl * c;  o[7] = spl * c;
}

// ---------------------------------------------------------------------------
// Single fused kernel: in-LDS prep, conv (2 px/lane), dual-chain qsim
// (16 px/wave), direct-Pauli measurement + FC. 256 blocks -> 1024 waves =
// 1 wave/SIMD; latency hiding from dual-chain ILP + shared coefficients.
// ---------------------------------------------------------------------------
__global__ __launch_bounds__(256) void qconv_kernel(
    const float* __restrict__ x, const float* __restrict__ cw,
    const float* __restrict__ cb, const float* __restrict__ u3p,
    const float* __restrict__ cu3p, const float* __restrict__ fcw,
    const float* __restrict__ fcb, float* __restrict__ out) {
  __shared__ float Us[40][8];
  __shared__ float Cs[40][8];
  __shared__ float Gs[640];
  __shared__ float FCWs[768];

  // ---- in-block prep (identical to rounds 10-11) ----
  {
    const int t = threadIdx.x;
    if (t < 40) u3fill(u3p + t * 3, Us[t]);
    if (t >= 64 && t < 104) u3fill(cu3p + (t - 64) * 3, Cs[t - 64]);
    for (int i = t; i < 768; i += 256) {
      int tt = i % 24;
      int stage = tt >> 3, w = tt & 7;
      float sc = (stage >= 1 && w >= 4) ? 2.0f : 1.0f;
      FCWs[i] = fcw[i] * sc;
    }
    __syncthreads();
    if (t == 0) {
#pragma unroll
      for (int j = 0; j < 8; ++j) Gs[j] = Us[0][j];
    } else if (t < 36) {
      int j = t - 1, b = j / 7, k = j % 7;
      float* dst = Gs + 8 + b * 112 + k * 16;
      const float* U = Us[b * 8 + k + 1];
      const float* C = Cs[b * 8 + k];
#pragma unroll
      for (int u = 0; u < 8; ++u) dst[u] = U[u];
      mm2(C, U, dst + 8);
    } else if (t < 40) {
      int b = t - 36;
      float* dst = Gs + 568 + b * 16;
      const float* U = Us[(b + 1) * 8];
      const float* C = Cs[b * 8 + 7];
#pragma unroll
      for (int u = 0; u < 8; ++u) dst[u] = U[u];
      mm2(U, C, dst + 8);
    } else if (t == 40) {
#pragma unroll
      for (int j = 0; j < 8; ++j) Gs[632 + j] = Cs[39][j];
    }
    __syncthreads();
  }

  const int lane = threadIdx.x & 63;
  const int wid = __builtin_amdgcn_readfirstlane(
      (int)((blockIdx.x * blockDim.x + threadIdx.x) >> 6));
  const int p0 = wid * 16;
  const int q = lane & 15;

  // ---- conv: lane = (px = lane>>3, oc = lane&7), 2 pixels (px, px+8) ----
  // All 16 pixels of a wave sit in the same image row (p0 % 16 == 0).
  float ang1, ang2;
  {
    const int px = lane >> 3;
    const int oc = lane & 7;
    const int p  = p0 + px;          // chain P pixel
    const int b  = p >> 12;
    const int hh = (p >> 6) & 63;
    const int w1 = p & 63;           // chain Q pixel column = w1 + 8
    float acc1 = cb[oc], acc2 = acc1;
#pragma unroll 4
    for (int ic = 0; ic < 16; ++ic) {
      const float* wp = cw + (oc * 16 + ic) * 9;
      const float* xp = x + (b * 16 + ic) * 4096;
#pragma unroll
      for (int kh = 0; kh < 3; ++kh) {
        int ih = hh + kh - 1;
        bool rok = (unsigned)ih < 64u;
        int ihc = rok ? ih : 0;
        const float* row = xp + ihc * 64;
#pragma unroll
        for (int kw = 0; kw < 3; ++kw) {
          float wv = wp[kh * 3 + kw];
          int iw1 = w1 + kw - 1;
          int iw2 = iw1 + 8;
          bool ok1 = rok && ((unsigned)iw1 < 64u);
          bool ok2 = rok && ((unsigned)iw2 < 64u);
          float x1 = row[(unsigned)iw1 < 64u ? iw1 : 0];
          float x2 = row[(unsigned)iw2 < 64u ? iw2 : 0];
          acc1 = fmaf(ok1 ? x1 : 0.0f, wv, acc1);
          acc2 = fmaf(ok2 ? x2 : 0.0f, wv, acc2);
        }
      }
    }
    ang1 = acc1; ang2 = acc2;
  }

  // ---- gather angles for both chains, build states (F0 folded) ----
  v2f Pr[16], Pi[16], Qr[16], Qi[16];
  {
    const int gb = (lane & 48) << 2;
    float aA[8], aB[8];
#pragma unroll
    for (int w = 0; w < 8; ++w) {
      aA[w] = bperm(ang1, gb + (w << 2));
      aB[w] = bperm(ang1, gb + ((8 + w) << 2));
    }
    initChain(aA, aB, Gs, q, Pr, Pi);
#pragma unroll
    for (int w = 0; w < 8; ++w) {
      aA[w] = bperm(ang2, gb + (w << 2));
      aB[w] = bperm(ang2, gb + ((8 + w) << 2));
    }
    initChain(aA, aB, Gs, q, Qr, Qi);
  }

  // ---- fused circuit, both chains sharing coefficients ----
  for (int b = 0; b < 5; ++b) {
    const float* base = Gs + 8 + b * 112;
    crossGD<4, 8>(Pr, Pi, Qr, Qi, base +  0, lane);
    crossGD<2, 4>(Pr, Pi, Qr, Qi, base + 16, lane);
    crossGD<1, 2>(Pr, Pi, Qr, Qi, base + 32, lane);
    f4D(Pr, Pi, Qr, Qi, base + 48, lane);
    f5D(Pr, Pi, Qr, Qi, base + 64);
    f6D(Pr, Pi, Qr, Qi, base + 80);
    f7D(Pr, Pi, Qr, Qi, base + 96);
    if (b < 4) f8pD(Pr, Pi, Qr, Qi, Gs + 568 + b * 16, lane);
  }
  f8D(Pr, Pi, Qr, Qi, Gs + 632, lane);

  // ---- measurements + FC, chain by chain ----
  float sg[4];
  sg[0] = (q & 8) ? -1.0f : 1.0f;
  sg[1] = (q & 4) ? -1.0f : 1.0f;
  sg[2] = (q & 2) ? -1.0f : 1.0f;
  sg[3] = (q & 1) ? -1.0f : 1.0f;

  const int j = q & 7;
  const bool isB = (q & 8) != 0;
  const int g = lane >> 4;

  v2f PT1[24], PT2[24];
  partials(Pr, Pi, sg, PT1);
  partials(Qr, Qi, sg, PT2);

  float mm1[24], mm2v[24];
#pragma unroll
  for (int t = 0; t < 24; ++t) {
    v2f v1 = PT1[t] + bfly2<8>(PT1[t]);
    v2f v2 = PT2[t] + bfly2<8>(PT2[t]);
    float s1 = isB ? v1.y : v1.x;
    float s2 = isB ? v2.y : v2.x;
    s1 += bfly<1>(s1);  s2 += bfly<1>(s2);
    s1 += bfly<2>(s1);  s2 += bfly<2>(s2);
    s1 += bfly<4>(s1);  s2 += bfly<4>(s2);
    mm1[t] = s1; mm2v[t] = s2;
  }

  const int pP = p0 + 2 * g + (isB ? 1 : 0);
  const int pQ = pP + 8;
  const int obP = (pP >> 12) * 131072 + (pP & 4095);
  const int obQ = (pQ >> 12) * 131072 + (pQ & 4095);
#pragma unroll
  for (int k = 0; k < 4; ++k) {
    const int ch = 4 * j + k;
    const float* wr = FCWs + ch * 24;
    float a1 = fcb[ch], a2 = a1;
#pragma unroll
    for (int u = 0; u < 24; ++u) {
      float wv = wr[u];
      a1 = fmaf(mm1[u], wv, a1);
      a2 = fmaf(mm2v[u], wv, a2);
    }
    out[obP + ch * 4096] = a1;
    out[obQ + ch * 4096] = a2;
  }
}

extern "C" void kernel_launch(void* const* d_in, const int* in_sizes, int n_in,
                              void* d_out, int out_size, void* d_ws, size_t ws_size,
                              hipStream_t stream) {
  const float* x      = (const float*)d_in[0];
  const float* conv_w = (const float*)d_in[1];
  const float* conv_b = (const float*)d_in[2];
  const float* u3p    = (const float*)d_in[3];
  const float* cu3p   = (const float*)d_in[4];
  const float* fcw    = (const float*)d_in[5];
  const float* fcb    = (const float*)d_in[6];
  float* out = (float*)d_out;

  qconv_kernel<<<256, 256, 0, stream>>>(x, conv_w, conv_b, u3p, cu3p,
                                        fcw, fcb, out);
}

// Round 14
// 106.803 us; speedup vs baseline: 1.0322x; 1.0322x over previous
//
#include <hip/hip_runtime.h>

typedef float v2f __attribute__((ext_vector_type(2)));

// ---------------------------------------------------------------------------
// Cross-lane helpers: masks 1,2,8 via DPP (VALU pipe), mask 4 via ds_swizzle;
// ds_bpermute only for the one-time angle gather.
// ---------------------------------------------------------------------------
template<int C>
__device__ __forceinline__ float dppmov(float x) {
  return __int_as_float(__builtin_amdgcn_update_dpp(0, __float_as_int(x), C, 0xF, 0xF, true));
}
template<int IMM>
__device__ __forceinline__ float dswz(float x) {
  return __int_as_float(__builtin_amdgcn_ds_swizzle(__float_as_int(x), IMM));
}
__device__ __forceinline__ float bperm(float x, int a) {
  return __int_as_float(__builtin_amdgcn_ds_bpermute(a, __float_as_int(x)));
}
template<int M>
__device__ __forceinline__ float bfly(float x) {
  if constexpr (M == 1)      return dppmov<0xB1>(x);   // quad_perm [1,0,3,2]
  else if constexpr (M == 2) return dppmov<0x4E>(x);   // quad_perm [2,3,0,1]
  else if constexpr (M == 8) return dppmov<0x128>(x);  // row_ror:8 == xor8
  else                       return dswz<0x101F>(x);   // M==4: bit-mode xor4
}
template<int M>
__device__ __forceinline__ v2f bfly2(v2f v) {
  v2f o; o.x = bfly<M>(v.x); o.y = bfly<M>(v.y); return o;
}
__device__ __forceinline__ v2f sp(float s) { v2f v; v.x = s; v.y = s; return v; }
__device__ __forceinline__ v2f vfma(v2f a, v2f b, v2f c) {
  return __builtin_elementwise_fma(a, b, c);
}

// ---------------------------------------------------------------------------
// Layout: 8 pixels/wave. Group g = lane>>4 holds the packed pixel pair in v2f.
// Amp i = q*16 + r, q = lane&15, r = 0..15. Wires 0..3 <-> q bits 3..0
// (masks 8,4,2,1); wires 4..7 <-> r bits 3..0.
// ---------------------------------------------------------------------------
template<int M, int CM>
__device__ __forceinline__ void crossG(v2f Sr[16], v2f Si[16],
    const float* g, int lane) {
  const bool hi = (lane & M) != 0;
  float fr, fi, gr, gi;
  if constexpr (CM == 0) {
    fr = hi ? g[6] : g[0]; fi = hi ? g[7] : g[1];
    gr = hi ? g[4] : g[2]; gi = hi ? g[5] : g[3];
  } else {
    const bool ct = (lane & CM) != 0;
    float f0r = hi ? g[6]  : g[0],  f0i = hi ? g[7]  : g[1];
    float g0r = hi ? g[4]  : g[2],  g0i = hi ? g[5]  : g[3];
    float f1r = hi ? g[14] : g[8],  f1i = hi ? g[15] : g[9];
    float g1r = hi ? g[12] : g[10], g1i = hi ? g[13] : g[11];
    fr = ct ? f1r : f0r; fi = ct ? f1i : f0i;
    gr = ct ? g1r : g0r; gi = ct ? g1i : g0i;
  }
  v2f vfr = sp(fr), vfi = sp(fi), vgr = sp(gr), vgi = sp(gi);
  v2f vfiN = sp(-fi), vgiN = sp(-gi);
#pragma unroll
  for (int r = 0; r < 16; ++r) {
    v2f pR = bfly2<M>(Sr[r]);
    v2f pI = bfly2<M>(Si[r]);
    v2f nR = vfma(vgiN, pI, vfma(vgr, pR, vfma(vfiN, Si[r], vfr * Sr[r])));
    v2f nI = vfma(vgi,  pR, vfma(vgr, pI, vfma(vfi,  Sr[r], vfr * Si[r])));
    Sr[r] = nR; Si[r] = nI;
  }
}

__device__ __forceinline__ void mixP(v2f& x0r, v2f& x0i, v2f& x1r, v2f& x1i,
    float m0r, float m0i, float m1r, float m1i,
    float m2r, float m2i, float m3r, float m3i) {
  v2f n0r = vfma(sp(-m1i), x1i, vfma(sp(m1r), x1r, vfma(sp(-m0i), x0i, sp(m0r) * x0r)));
  v2f n0i = vfma(sp( m1i), x1r, vfma(sp(m1r), x1i, vfma(sp( m0i), x0r, sp(m0r) * x0i)));
  v2f n1r = vfma(sp(-m3i), x1i, vfma(sp(m3r), x1r, vfma(sp(-m2i), x0i, sp(m2r) * x0r)));
  v2f n1i = vfma(sp( m3i), x1r, vfma(sp(m3r), x1i, vfma(sp( m2i), x0r, sp(m2r) * x0i)));
  x0r = n0r; x0i = n0i; x1r = n1r; x1i = n1i;
}

// F4: fused u3(w4)+cu3(3->4): ctrl lane bit0 (wire 3), target r bit3.
__device__ __forceinline__ void f4N(v2f Sr[16], v2f Si[16],
    const float* g, int lane) {
  const bool ct = (lane & 1) != 0;
  float m[8];
#pragma unroll
  for (int jj = 0; jj < 8; ++jj) m[jj] = ct ? g[8 + jj] : g[jj];
#pragma unroll
  for (int r = 0; r < 8; ++r)
    mixP(Sr[r], Si[r], Sr[r + 8], Si[r + 8],
         m[0], m[1], m[2], m[3], m[4], m[5], m[6], m[7]);
}
// F5: ctrl r bit3, target r bit2.
__device__ __forceinline__ void f5N(v2f Sr[16], v2f Si[16], const float* g) {
#pragma unroll
  for (int r = 0; r < 4; ++r)
    mixP(Sr[r], Si[r], Sr[r + 4], Si[r + 4],
         g[0], g[1], g[2], g[3], g[4], g[5], g[6], g[7]);
#pragma unroll
  for (int r = 8; r < 12; ++r)
    mixP(Sr[r], Si[r], Sr[r + 4], Si[r + 4],
         g[8], g[9], g[10], g[11], g[12], g[13], g[14], g[15]);
}
// F6: ctrl r bit2, target r bit1.
__device__ __forceinline__ void f6N(v2f Sr[16], v2f Si[16], const float* g) {
#pragma unroll
  for (int t = 0; t < 4; ++t) {
    const int r0 = (t >> 1) * 8 + (t & 1);
    mixP(Sr[r0], Si[r0], Sr[r0 + 2], Si[r0 + 2],
         g[0], g[1], g[2], g[3], g[4], g[5], g[6], g[7]);
    const int r1 = r0 + 4;
    mixP(Sr[r1], Si[r1], Sr[r1 + 2], Si[r1 + 2],
         g[8], g[9], g[10], g[11], g[12], g[13], g[14], g[15]);
  }
}
// F7: ctrl r bit1, target r bit0.
__device__ __forceinline__ void f7N(v2f Sr[16], v2f Si[16], const float* g) {
#pragma unroll
  for (int t = 0; t < 4; ++t) {
    const int r0 = t * 4;
    mixP(Sr[r0], Si[r0], Sr[r0 + 1], Si[r0 + 1],
         g[0], g[1], g[2], g[3], g[4], g[5], g[6], g[7]);
    const int r1 = r0 + 2;
    mixP(Sr[r1], Si[r1], Sr[r1 + 1], Si[r1 + 1],
         g[8], g[9], g[10], g[11], g[12], g[13], g[14], g[15]);
  }
}
// F8': fused cu3(7->0)+next u3(w0): ctrl r bit0, target mask 8.
__device__ __forceinline__ void f8pN(v2f Sr[16], v2f Si[16],
    const float* g, int lane) {
  const bool hi = (lane & 8) != 0;
  float fr[2], fi[2], gr[2], gi[2];
  fr[0] = hi ? g[6]  : g[0];  fi[0] = hi ? g[7]  : g[1];
  gr[0] = hi ? g[4]  : g[2];  gi[0] = hi ? g[5]  : g[3];
  fr[1] = hi ? g[14] : g[8];  fi[1] = hi ? g[15] : g[9];
  gr[1] = hi ? g[12] : g[10]; gi[1] = hi ? g[13] : g[11];
#pragma unroll
  for (int r = 0; r < 16; ++r) {
    const int m = r & 1;
    v2f pR = bfly2<8>(Sr[r]);
    v2f pI = bfly2<8>(Si[r]);
    v2f nR = vfma(sp(-gi[m]), pI, vfma(sp(gr[m]), pR, vfma(sp(-fi[m]), Si[r], sp(fr[m]) * Sr[r])));
    v2f nI = vfma(sp( gi[m]), pR, vfma(sp(gr[m]), pI, vfma(sp( fi[m]), Sr[r], sp(fr[m]) * Si[r])));
    Sr[r] = nR; Si[r] = nI;
  }
}
// F8 final standalone cu3(7->0): odd r only, target mask 8.
__device__ __forceinline__ void f8N(v2f Sr[16], v2f Si[16],
    const float* g, int lane) {
  const bool hi = (lane & 8) != 0;
  const float fr = hi ? g[6] : g[0], fi = hi ? g[7] : g[1];
  const float gr = hi ? g[4] : g[2], gi = hi ? g[5] : g[3];
#pragma unroll
  for (int r = 1; r < 16; r += 2) {
    v2f pR = bfly2<8>(Sr[r]);
    v2f pI = bfly2<8>(Si[r]);
    v2f nR = vfma(sp(-gi), pI, vfma(sp(gr), pR, vfma(sp(-fi), Si[r], sp(fr) * Sr[r])));
    v2f nI = vfma(sp( gi), pR, vfma(sp(gr), pI, vfma(sp( fi), Sr[r], sp(fr) * Si[r])));
    Sr[r] = nR; Si[r] = nI;
  }
}

// Off-diagonal pair sum for a cross wire (mask M): per-lane partials.
template<int M>
__device__ __forceinline__ void crossO(const v2f Sr[16], const v2f Si[16],
                                       v2f& re, v2f& im) {
  v2f r = sp(0.0f), i = sp(0.0f);
#pragma unroll
  for (int k = 0; k < 16; ++k) {
    v2f pr = bfly2<M>(Sr[k]);
    v2f pi = bfly2<M>(Si[k]);
    r = vfma(Sr[k], pr, r);
    r = vfma(Si[k], pi, r);
    i = vfma(Si[k], pr, i);
    i = vfma(-Sr[k], pi, i);
  }
  re = r; im = i;
}

// ---------------------------------------------------------------------------
// Prep helpers.
// ---------------------------------------------------------------------------
__device__ __forceinline__ void mm2(const float* A, const float* B, float* D) {
  D[0] = A[0]*B[0] - A[1]*B[1] + A[2]*B[4] - A[3]*B[5];
  D[1] = A[0]*B[1] + A[1]*B[0] + A[2]*B[5] + A[3]*B[4];
  D[2] = A[0]*B[2] - A[1]*B[3] + A[2]*B[6] - A[3]*B[7];
  D[3] = A[0]*B[3] + A[1]*B[2] + A[2]*B[7] + A[3]*B[6];
  D[4] = A[4]*B[0] - A[5]*B[1] + A[6]*B[4] - A[7]*B[5];
  D[5] = A[4]*B[1] + A[5]*B[0] + A[6]*B[5] + A[7]*B[4];
  D[6] = A[4]*B[2] - A[5]*B[3] + A[6]*B[6] - A[7]*B[7];
  D[7] = A[4]*B[3] + A[5]*B[2] + A[6]*B[7] + A[7]*B[6];
}
__device__ __forceinline__ void u3fill(const float* src, float* o) {
  float th = src[0], ph = src[1], lam = src[2];
  float c = cosf(0.5f * th), s = sinf(0.5f * th);
  float cl = cosf(lam), sl = sinf(lam);
  float cp = cosf(ph), spv = sinf(ph);
  float cpl = cosf(ph + lam), spl = sinf(ph + lam);
  o[0] = c;        o[1] = 0.0f;
  o[2] = -cl * s;  o[3] = -sl * s;
  o[4] = cp * s;   o[5] = spv * s;
  o[6] = cpl * c;  o[7] = spl * c;
}

// ---------------------------------------------------------------------------
// Single fused kernel (round-11 structure, best measured) + FC weight rows
// padded to stride 25 in LDS: with stride 24, the 8 concurrent ch-addresses
// in the FC dot sat on one bank (96 mod 32 == 0 -> 8-way conflict, 643K
// conflict cycles in r11's PMC). 25 is coprime with 32 -> conflict-free.
// ---------------------------------------------------------------------------
__global__ __launch_bounds__(256) void qconv_kernel(
    const float* __restrict__ x, const float* __restrict__ cw,
    const float* __restrict__ cb, const float* __restrict__ u3p,
    const float* __restrict__ cu3p, const float* __restrict__ fcw,
    const float* __restrict__ fcb, float* __restrict__ out) {
  __shared__ float Us[40][8];
  __shared__ float Cs[40][8];
  __shared__ float Gs[640];
  __shared__ float FCWs[800];   // 32 channels x stride 25 (24 used + 1 pad)

  // ---- in-block prep ----
  {
    const int t = threadIdx.x;
    if (t < 40) u3fill(u3p + t * 3, Us[t]);
    if (t >= 64 && t < 104) u3fill(cu3p + (t - 64) * 3, Cs[t - 64]);
    for (int i = t; i < 768; i += 256) {
      int ch = i / 24, tt = i % 24;
      int stage = tt >> 3, w = tt & 7;
      float sc = (stage >= 1 && w >= 4) ? 2.0f : 1.0f;
      FCWs[ch * 25 + tt] = fcw[i] * sc;
    }
    __syncthreads();
    if (t == 0) {
#pragma unroll
      for (int j = 0; j < 8; ++j) Gs[j] = Us[0][j];
    } else if (t < 36) {
      int j = t - 1, b = j / 7, k = j % 7;
      float* dst = Gs + 8 + b * 112 + k * 16;
      const float* U = Us[b * 8 + k + 1];
      const float* C = Cs[b * 8 + k];
#pragma unroll
      for (int u = 0; u < 8; ++u) dst[u] = U[u];
      mm2(C, U, dst + 8);
    } else if (t < 40) {
      int b = t - 36;
      float* dst = Gs + 568 + b * 16;
      const float* U = Us[(b + 1) * 8];
      const float* C = Cs[b * 8 + 7];
#pragma unroll
      for (int u = 0; u < 8; ++u) dst[u] = U[u];
      mm2(U, C, dst + 8);
    } else if (t == 40) {
#pragma unroll
      for (int j = 0; j < 8; ++j) Gs[632 + j] = Cs[39][j];
    }
    __syncthreads();
  }

  const int lane = threadIdx.x & 63;
  const int wid = __builtin_amdgcn_readfirstlane(
      (int)((blockIdx.x * blockDim.x + threadIdx.x) >> 6));
  const int p0 = wid * 8;
  const int q = lane & 15;

  // ---- conv: lane = (px = lane>>3, oc = lane&7) ----
  float ang;
  {
    const int px = lane >> 3;
    const int oc = lane & 7;
    const int p  = p0 + px;
    const int b  = p >> 12;
    const int hh = (p >> 6) & 63;
    const int wim = p & 63;
    float acc = cb[oc];
#pragma unroll 4
    for (int ic = 0; ic < 16; ++ic) {
      const float* wp = cw + (oc * 16 + ic) * 9;
      const float* xp = x + (b * 16 + ic) * 4096;
#pragma unroll
      for (int kh = 0; kh < 3; ++kh) {
        int ih = hh + kh - 1;
        bool rok = (unsigned)ih < 64u;
        int ihc = rok ? ih : 0;
#pragma unroll
        for (int kw = 0; kw < 3; ++kw) {
          int iw = wim + kw - 1;
          bool ok = rok && ((unsigned)iw < 64u);
          int iwc = ((unsigned)iw < 64u) ? iw : 0;
          float xv = xp[ihc * 64 + iwc];
          acc = fmaf(ok ? xv : 0.0f, wp[kh * 3 + kw], acc);
        }
      }
    }
    ang = acc;
  }

  // ---- gather 16 angles, build product state with F0 folded ----
  v2f Sr[16], Si[16];
  {
    const int gb = (lane & 48) << 2;
    float aA[8], aB[8];
#pragma unroll
    for (int w = 0; w < 8; ++w) {
      aA[w] = bperm(ang, gb + (w << 2));
      aB[w] = bperm(ang, gb + ((8 + w) << 2));
    }
    float cA[8], sA[8], cB[8], sB[8];
#pragma unroll
    for (int w = 0; w < 8; ++w) {
      __sincosf(0.5f * aA[w], &sA[w], &cA[w]);
      __sincosf(0.5f * aB[w], &sB[w], &cB[w]);
    }
    v2f c0; c0.x = cA[0]; c0.y = cB[0];
    v2f s0; s0.x = sA[0]; s0.y = sB[0];
    v2f c0r = vfma(sp(Gs[2]), s0, sp(Gs[0]) * c0);
    v2f c0i = vfma(sp(Gs[3]), s0, sp(Gs[1]) * c0);
    v2f s0r = vfma(sp(Gs[6]), s0, sp(Gs[4]) * c0);
    v2f s0i = vfma(sp(Gs[7]), s0, sp(Gs[5]) * c0);
    const bool w0 = (q & 8) != 0;
    v2f selR = w0 ? s0r : c0r;
    v2f selI = w0 ? s0i : c0i;
    float fA = ((q & 4) ? sA[1] : cA[1]) * ((q & 2) ? sA[2] : cA[2])
             * ((q & 1) ? sA[3] : cA[3]);
    float fB = ((q & 4) ? sB[1] : cB[1]) * ((q & 2) ? sB[2] : cB[2])
             * ((q & 1) ? sB[3] : cB[3]);
    v2f uu[4], vv[4];
    uu[0].x = cA[6]*cA[7]; uu[1].x = cA[6]*sA[7];
    uu[2].x = sA[6]*cA[7]; uu[3].x = sA[6]*sA[7];
    uu[0].y = cB[6]*cB[7]; uu[1].y = cB[6]*sB[7];
    uu[2].y = sB[6]*cB[7]; uu[3].y = sB[6]*sB[7];
    float vA0 = fA * cA[4], vA1 = fA * sA[4];
    float vB0 = fB * cB[4], vB1 = fB * sB[4];
    vv[0].x = vA0*cA[5]; vv[1].x = vA0*sA[5];
    vv[2].x = vA1*cA[5]; vv[3].x = vA1*sA[5];
    vv[0].y = vB0*cB[5]; vv[1].y = vB0*sB[5];
    vv[2].y = vB1*cB[5]; vv[3].y = vB1*sB[5];
#pragma unroll
    for (int r = 0; r < 16; ++r) {
      v2f base = vv[r >> 2] * uu[r & 3];
      Sr[r] = selR * base;
      Si[r] = selI * base;
    }
  }

  // ---- fused circuit (F0 applied in init) ----
  for (int b = 0; b < 5; ++b) {
    const float* base = Gs + 8 + b * 112;
    crossG<4, 8>(Sr, Si, base +  0, lane);
    crossG<2, 4>(Sr, Si, base + 16, lane);
    crossG<1, 2>(Sr, Si, base + 32, lane);
    f4N(Sr, Si, base + 48, lane);
    f5N(Sr, Si, base + 64);
    f6N(Sr, Si, base + 80);
    f7N(Sr, Si, base + 96);
    if (b < 4) f8pN(Sr, Si, Gs + 568 + b * 16, lane);
  }
  f8N(Sr, Si, Gs + 632, lane);

  // ---- per-lane measurement partials ----
  float sg[4];
  sg[0] = (q & 8) ? -1.0f : 1.0f;
  sg[1] = (q & 4) ? -1.0f : 1.0f;
  sg[2] = (q & 2) ? -1.0f : 1.0f;
  sg[3] = (q & 1) ? -1.0f : 1.0f;

  v2f PT[24];
  {
    v2f re0, im0, re1, im1, re2, im2, re3, im3;
    crossO<8>(Sr, Si, re0, im0);
    crossO<4>(Sr, Si, re1, im1);
    crossO<2>(Sr, Si, re2, im2);
    crossO<1>(Sr, Si, re3, im3);
    PT[8]  = re0; PT[9]  = re1; PT[10] = re2; PT[11] = re3;
    PT[16] = sp(sg[0]) * im0; PT[17] = sp(sg[1]) * im1;
    PT[18] = sp(sg[2]) * im2; PT[19] = sp(sg[3]) * im3;

    v2f P[16];
#pragma unroll
    for (int r = 0; r < 16; ++r) P[r] = vfma(Si[r], Si[r], Sr[r] * Sr[r]);
    v2f t01[8];
#pragma unroll
    for (int k = 0; k < 8; ++k) t01[k] = P[2*k] + P[2*k+1];
    v2f q0 = t01[0] + t01[1], q1 = t01[2] + t01[3];
    v2f q2 = t01[4] + t01[5], q3 = t01[6] + t01[7];
    v2f h0 = q0 + q1, h1 = q2 + q3;
    v2f p  = h0 + h1;
    PT[4] = h0 - h1;
    PT[5] = (q0 - q1) + (q2 - q3);
    PT[6] = (t01[0]-t01[1]) + (t01[2]-t01[3])
          + (t01[4]-t01[5]) + (t01[6]-t01[7]);
    PT[7] = (P[0]-P[1]) + (P[2]-P[3]) + (P[4]-P[5]) + (P[6]-P[7])
          + (P[8]-P[9]) + (P[10]-P[11]) + (P[12]-P[13]) + (P[14]-P[15]);
    PT[0] = sp(sg[0]) * p; PT[1] = sp(sg[1]) * p;
    PT[2] = sp(sg[2]) * p; PT[3] = sp(sg[3]) * p;

    v2f re, im;
    re = sp(0.0f); im = sp(0.0f);
#pragma unroll
    for (int r = 0; r < 8; ++r) {
      re = vfma(Sr[r], Sr[r+8], re); re = vfma(Si[r], Si[r+8], re);
      im = vfma(Si[r], Sr[r+8], im); im = vfma(-Sr[r], Si[r+8], im);
    }
    PT[12] = re; PT[20] = im;
    re = sp(0.0f); im = sp(0.0f);
#pragma unroll
    for (int t = 0; t < 8; ++t) {
      const int lo = (t & 3) + (t >> 2) * 8;
      re = vfma(Sr[lo], Sr[lo+4], re); re = vfma(Si[lo], Si[lo+4], re);
      im = vfma(Si[lo], Sr[lo+4], im); im = vfma(-Sr[lo], Si[lo+4], im);
    }
    PT[13] = re; PT[21] = im;
    re = sp(0.0f); im = sp(0.0f);
#pragma unroll
    for (int t = 0; t < 8; ++t) {
      const int lo = (t & 1) + (t >> 1) * 4;
      re = vfma(Sr[lo], Sr[lo+2], re); re = vfma(Si[lo], Si[lo+2], re);
      im = vfma(Si[lo], Sr[lo+2], im); im = vfma(-Sr[lo], Si[lo+2], im);
    }
    PT[14] = re; PT[22] = im;
    re = sp(0.0f); im = sp(0.0f);
#pragma unroll
    for (int t = 0; t < 8; ++t) {
      const int lo = 2 * t;
      re = vfma(Sr[lo], Sr[lo+1], re); re = vfma(Si[lo], Si[lo+1], re);
      im = vfma(Si[lo], Sr[lo+1], im); im = vfma(-Sr[lo], Si[lo+1], im);
    }
    PT[15] = re; PT[23] = im;
  }

  // ---- group-reduce partials to uniform values, THEN per-channel FC ----
  const int j = q & 7;
  const bool isB = (q & 8) != 0;
  float mm[24];
#pragma unroll
  for (int t = 0; t < 24; ++t) {
    v2f v = PT[t] + bfly2<8>(PT[t]);   // pair over mask 8 (both pixels)
    float s = isB ? v.y : v.x;          // keep own pixel
    s += bfly<1>(s);
    s += bfly<2>(s);
    s += bfly<4>(s);                    // completes the 16-lane sum
    mm[t] = s;
  }

  const int g = lane >> 4;
  const int p = p0 + 2 * g + (isB ? 1 : 0);
  const int ob = (p >> 12) * 131072 + (p & 4095);
#pragma unroll
  for (int k = 0; k < 4; ++k) {
    const int ch = 4 * j + k;
    const float* wr = FCWs + ch * 25;
    float acc = fcb[ch];
#pragma unroll
    for (int u = 0; u < 24; ++u) acc = fmaf(mm[u], wr[u], acc);
    out[ob + ch * 4096] = acc;
  }
}

extern "C" void kernel_launch(void* const* d_in, const int* in_sizes, int n_in,
                              void* d_out, int out_size, void* d_ws, size_t ws_size,
                              hipStream_t stream) {
  const float* x      = (const float*)d_in[0];
  const float* conv_w = (const float*)d_in[1];
  const float* conv_b = (const float*)d_in[2];
  const float* u3p    = (const float*)d_in[3];
  const float* cu3p   = (const float*)d_in[4];
  const float* fcw    = (const float*)d_in[5];
  const float* fcb    = (const float*)d_in[6];
  float* out = (float*)d_out;

  qconv_kernel<<<512, 256, 0, stream>>>(x, conv_w, conv_b, u3p, cu3p,
                                        fcw, fcb, out);
}